// Round 7
// baseline (172.172 us; speedup 1.0000x reference)
//
#include <hip/hip_runtime.h>

#define FEAT 128              // elements per row (int8 row = 128 bytes)
#define EPG 4                 // edges per 8-lane group
#define CNT_SHIFT 25          // deg in bits [25..31]
#define FIX_SCALE 32768.0f    // 2^15 fixed point for (sim+2) in [0,3.01]
#define INV_FIX (1.0f/32768.0f)
#define EPS 1e-8f

// native vector type (HIP's uint4 is a struct; __builtin_nontemporal_load
// needs a scalar/vector type to emit global_load_dwordx4 ... nt)
typedef unsigned uv4 __attribute__((ext_vector_type(4)));

__device__ __forceinline__ uv4 ntload(const void* p) {
#if __has_builtin(__builtin_nontemporal_load)
    return __builtin_nontemporal_load((const uv4*)p);
#else
    return *(const uv4*)p;
#endif
}

// physical XCD id (gfx940+). Partition by VALUE -> correct regardless of
// dispatch->XCD mapping (G16-safe).
__device__ __forceinline__ unsigned xcc_id() {
    unsigned x;
    asm volatile("s_getreg_b32 %0, hwreg(HW_REG_XCC_ID)" : "=s"(x));
    return x & 7u;
}

__device__ __forceinline__ unsigned pack_sim(float sim) {
    return (1u << CNT_SHIFT) | (unsigned)((sim + 2.0f) * FIX_SCALE + 0.5f);
}

__device__ __forceinline__ int dot4(unsigned a, unsigned b, int c) {
#if __has_builtin(__builtin_amdgcn_sdot4)
    return __builtin_amdgcn_sdot4(a, b, c, false);
#else
    c += (int)(signed char)(a)        * (int)(signed char)(b);
    c += (int)(signed char)(a >> 8)   * (int)(signed char)(b >> 8);
    c += (int)(signed char)(a >> 16)  * (int)(signed char)(b >> 16);
    c += (int)(signed char)(a >> 24)  * (int)(signed char)(b >> 24);
    return c;
#endif
}

__device__ __forceinline__ int dot16(uv4 a, uv4 b) {
    int c = dot4(a.x, b.x, 0);
    c = dot4(a.y, b.y, c);
    c = dot4(a.z, b.z, c);
    return dot4(a.w, b.w, c);
}

// Kernel 1: per-node int8 quantization (q=rint(127 f/amax)) + invq=1/||q||.
// feat reads and table writes are NT (streaming, no reuse before edge kernel).
__global__ void quantize_kernel(const float* __restrict__ feat,
                                unsigned* __restrict__ tab32,
                                float* __restrict__ invq,
                                int num_nodes) {
    const int lane = threadIdx.x & 63;
    const int wpb = blockDim.x >> 6;
    int n = blockIdx.x * wpb + (threadIdx.x >> 6);
    const int stride = gridDim.x * wpb;
    for (; n < num_nodes; n += stride) {
        // lane loads float4 (4 elems): 64*16B = 256B = half row; two halves via x2
        const uv4 u0 = ntload(feat + (size_t)n * FEAT + lane * 2);
        const float vx = __uint_as_float(u0.x);
        const float vy = __uint_as_float(u0.y);
        // (only 2 of 4 used per lane for the amax/norm math below; the row is
        //  covered because 64 lanes * 2 = 128.  u0.z/u0.w belong to lane+? No:
        //  stride is lane*2 floats => load float2 worth; use .x/.y only.)
        float am = fmaxf(fabsf(vx), fabsf(vy));
        am = fmaxf(am, __shfl_xor(am, 32, 64));
        am = fmaxf(am, __shfl_xor(am, 16, 64));
        am = fmaxf(am, __shfl_xor(am, 8, 64));
        am = fmaxf(am, __shfl_xor(am, 4, 64));
        am = fmaxf(am, __shfl_xor(am, 2, 64));
        am = fmaxf(am, __shfl_xor(am, 1, 64));
        const float sc = (am > 0.0f) ? (127.0f / am) : 0.0f;
        const int qx = (int)rintf(vx * sc);
        const int qy = (int)rintf(vy * sc);
        int nq = qx * qx + qy * qy;
        nq += __shfl_xor(nq, 32, 64);
        nq += __shfl_xor(nq, 16, 64);
        nq += __shfl_xor(nq, 8, 64);
        nq += __shfl_xor(nq, 4, 64);
        nq += __shfl_xor(nq, 2, 64);
        nq += __shfl_xor(nq, 1, 64);
        // pack 2 int8 per lane -> 16 bits; pair lanes via shfl to make u32
        const unsigned two = (unsigned)((qx & 0xFF) | ((qy & 0xFF) << 8));
        const unsigned other = __shfl_xor(two, 1, 64);
        if ((lane & 1) == 0) {
            const unsigned word = two | (other << 16);
#if __has_builtin(__builtin_nontemporal_store)
            __builtin_nontemporal_store(word, tab32 + (size_t)n * (FEAT / 4) + (lane >> 1));
#else
            tab32[(size_t)n * (FEAT / 4) + (lane >> 1)] = word;
#endif
        }
        if (lane == 0)
            invq[n] = (nq > 0) ? (1.0f / sqrtf((float)nq)) : 0.0f;
    }
}

// Kernel 2: FLAT edge kernel. 8 lanes/edge-group, 4 consecutive edges/group.
// All gathers + index loads are NON-TEMPORAL: they stream from L3 without
// evicting the L2-resident accumulator copies (thrash fix).
template <int NCOPY>
__global__ void edge_i8_flat(const unsigned char* __restrict__ tab,
                             const int* __restrict__ ei,
                             const float* __restrict__ invq,
                             unsigned* __restrict__ acc,
                             int num_edges, int num_nodes, int aligned4) {
    unsigned* myacc = acc;
    if (NCOPY == 8) myacc = acc + (size_t)xcc_id() * num_nodes;

    const int sub = threadIdx.x & 7;
    const int gid = blockIdx.x * (blockDim.x >> 3) + (threadIdx.x >> 3);
    const int e0 = gid * EPG;
    if (e0 >= num_edges) return;

    int s[EPG], d[EPG];
    const bool fast = aligned4 && (e0 + EPG <= num_edges);
    if (fast) {
        const uv4 si = ntload(ei + e0);
        const uv4 di = ntload(ei + num_edges + e0);
        s[0] = (int)si.x; s[1] = (int)si.y; s[2] = (int)si.z; s[3] = (int)si.w;
        d[0] = (int)di.x; d[1] = (int)di.y; d[2] = (int)di.z; d[3] = (int)di.w;
    } else {
#pragma unroll
        for (int k = 0; k < EPG; ++k) {
            const int e = min(e0 + k, num_edges - 1);
            s[k] = ei[e];
            d[k] = ei[num_edges + e];
        }
    }

    uv4 a[EPG], b[EPG];
#pragma unroll
    for (int k = 0; k < EPG; ++k) {
        a[k] = ntload(tab + (size_t)s[k] * FEAT + sub * 16);
        b[k] = ntload(tab + (size_t)d[k] * FEAT + sub * 16);
    }

    int p[EPG];
#pragma unroll
    for (int k = 0; k < EPG; ++k) p[k] = dot16(a[k], b[k]);
#pragma unroll
    for (int k = 0; k < EPG; ++k) {
        p[k] += __shfl_xor(p[k], 1, 64);
        p[k] += __shfl_xor(p[k], 2, 64);
        p[k] += __shfl_xor(p[k], 4, 64);
    }

    // lane 2k -> src of edge k, lane 2k+1 -> dst of edge k (static selects)
    int myidx = s[0];
    if (sub == 1) myidx = d[0];
    else if (sub == 2) myidx = s[1];
    else if (sub == 3) myidx = d[1];
    else if (sub == 4) myidx = s[2];
    else if (sub == 5) myidx = d[2];
    else if (sub == 6) myidx = s[3];
    else if (sub == 7) myidx = d[3];

    int mydot = p[0];
    if (sub >= 6) mydot = p[3];
    else if (sub >= 4) mydot = p[2];
    else if (sub >= 2) mydot = p[1];

    const float msc = invq[myidx];          // cached: invq stays L2-resident
    const float prod = msc * __shfl_xor(msc, 1, 64);

    if (fast || (e0 + (sub >> 1)) < num_edges) {
        const unsigned pk = pack_sim((float)mydot * prod);
        if (NCOPY == 8) {
            __hip_atomic_fetch_add(&myacc[myidx], pk, __ATOMIC_RELAXED,
                                   __HIP_MEMORY_SCOPE_WORKGROUP);
        } else {
            __hip_atomic_fetch_add(&myacc[myidx], pk, __ATOMIC_RELAXED,
                                   __HIP_MEMORY_SCOPE_AGENT);
        }
    }
}

// ---- fallback (ws too small): fp32 gathers, device-scope ----
__global__ void norms_inv_kernel(const float* __restrict__ feat,
                                 float* __restrict__ inv,
                                 int num_nodes) {
    const int lane = threadIdx.x & 63;
    const int wpb = blockDim.x >> 6;
    int n = blockIdx.x * wpb + (threadIdx.x >> 6);
    const int stride = gridDim.x * wpb;
    for (; n < num_nodes; n += stride) {
        const float2 v = *reinterpret_cast<const float2*>(feat + (size_t)n * FEAT + lane * 2);
        float s = v.x * v.x + v.y * v.y;
        s += __shfl_xor(s, 32, 64);
        s += __shfl_xor(s, 16, 64);
        s += __shfl_xor(s, 8, 64);
        s += __shfl_xor(s, 4, 64);
        s += __shfl_xor(s, 2, 64);
        s += __shfl_xor(s, 1, 64);
        if (lane == 0) inv[n] = 1.0f / fmaxf(sqrtf(s), EPS);
    }
}

__global__ void edge_f32_kernel(const float* __restrict__ feat,
                                const int* __restrict__ ei,
                                const float* __restrict__ inv,
                                unsigned* __restrict__ acc,
                                int num_edges) {
    const int sub = threadIdx.x & 31;
    const int gpb = blockDim.x >> 5;
    const int group = blockIdx.x * gpb + (threadIdx.x >> 5);
    const int ngroups = gridDim.x * gpb;
    for (int e = group; e < num_edges; e += ngroups) {
        const int s = ei[e];
        const int d = ei[num_edges + e];
        const float4 a = *reinterpret_cast<const float4*>(feat + (size_t)s * FEAT + sub * 4);
        const float4 b = *reinterpret_cast<const float4*>(feat + (size_t)d * FEAT + sub * 4);
        float p = a.x * b.x + a.y * b.y + a.z * b.z + a.w * b.w;
        p += __shfl_xor(p, 16, 64);
        p += __shfl_xor(p, 8, 64);
        p += __shfl_xor(p, 4, 64);
        p += __shfl_xor(p, 2, 64);
        p += __shfl_xor(p, 1, 64);
        const unsigned pk = pack_sim(p * inv[s] * inv[d]);
        if (sub == 0) atomicAdd(&acc[s], pk);
        else if (sub == 1) atomicAdd(&acc[d], pk);
    }
}

// Kernel 3: decode across copies.
__global__ void final_kernel(const unsigned* __restrict__ acc,
                             float* __restrict__ out,
                             int num_nodes, int ncopies) {
    const int i = blockIdx.x * blockDim.x + threadIdx.x;
    if (i < num_nodes) {
        unsigned cnt = 0, fx = 0;
        for (int c = 0; c < ncopies; ++c) {
            const unsigned x = acc[(size_t)c * num_nodes + i];
            cnt += x >> CNT_SHIFT;
            fx += x & ((1u << CNT_SHIFT) - 1u);
        }
        out[i] = cnt ? ((float)fx * INV_FIX - 2.0f * (float)cnt) / (float)cnt : 1.0f;
    }
}

extern "C" void kernel_launch(void* const* d_in, const int* in_sizes, int n_in,
                              void* d_out, int out_size, void* d_ws, size_t ws_size,
                              hipStream_t stream) {
    const float* feat = (const float*)d_in[0];
    const int* ei = (const int*)d_in[1];
    const int num_nodes = in_sizes[0] / FEAT;     // 100000
    const int num_edges = in_sizes[1] / 2;        // 1600000
    float* out = (float*)d_out;

    unsigned* acc = (unsigned*)d_ws;
    const size_t need8 = (size_t)num_nodes *
        (8 * sizeof(unsigned) + sizeof(float) + FEAT * sizeof(unsigned char));
    const size_t need1 = (size_t)num_nodes *
        (1 * sizeof(unsigned) + sizeof(float) + FEAT * sizeof(unsigned char));

    if (ws_size >= need1) {
        const int ncopy = (ws_size >= need8) ? 8 : 1;
        const size_t acc_bytes = (size_t)num_nodes * ncopy * sizeof(unsigned);
        float* invq = (float*)((char*)d_ws + acc_bytes);
        unsigned* tab32 = (unsigned*)(invq + num_nodes);
        hipMemsetAsync(acc, 0, acc_bytes, stream);
        {
            const int wpb = 4;
            int blocks = (num_nodes + wpb - 1) / wpb;
            if (blocks > 25000) blocks = 25000;
            quantize_kernel<<<blocks, 256, 0, stream>>>(feat, tab32, invq, num_nodes);
        }
        {
            const int epb = (256 / 8) * EPG;                  // 128 edges/block
            const int blocks = (num_edges + epb - 1) / epb;   // 12500 exact fit
            const int aligned4 = ((num_edges & 3) == 0) ? 1 : 0;
            if (ncopy == 8) {
                edge_i8_flat<8><<<blocks, 256, 0, stream>>>(
                    (const unsigned char*)tab32, ei, invq, acc,
                    num_edges, num_nodes, aligned4);
            } else {
                edge_i8_flat<1><<<blocks, 256, 0, stream>>>(
                    (const unsigned char*)tab32, ei, invq, acc,
                    num_edges, num_nodes, aligned4);
            }
        }
        final_kernel<<<(num_nodes + 255) / 256, 256, 0, stream>>>(acc, out, num_nodes, ncopy);
    } else {
        float* inv = (float*)((char*)d_ws + (size_t)num_nodes * sizeof(unsigned));
        hipMemsetAsync(acc, 0, (size_t)num_nodes * sizeof(unsigned), stream);
        {
            const int wpb = 4;
            int blocks = (num_nodes + wpb - 1) / wpb;
            norms_inv_kernel<<<blocks, 256, 0, stream>>>(feat, inv, num_nodes);
        }
        edge_f32_kernel<<<4096, 256, 0, stream>>>(feat, ei, inv, acc, num_edges);
        final_kernel<<<(num_nodes + 255) / 256, 256, 0, stream>>>(acc, out, num_nodes, 1);
    }
}

// Round 8
// 151.706 us; speedup vs baseline: 1.1349x; 1.1349x over previous
//
#include <hip/hip_runtime.h>

#define FEAT 128              // elements per row (int8 row = 128 bytes)
#define EPG 4                 // edges per 8-lane group
#define CHN 16000             // nodes per LDS chunk (64000 B static LDS)
#define CNT_SHIFT 24          // count in bits [24..31] of packed u32
#define SIM_SCALE 16384.0f    // 2^14 fixed point for (sim+2) in [0,3.0] -> <= 49152 (u16 ok)
#define INV_SIM (1.0f/16384.0f)
#define EPS 1e-8f

typedef unsigned uv4 __attribute__((ext_vector_type(4)));
typedef unsigned short us4 __attribute__((ext_vector_type(4)));

__device__ __forceinline__ int dot4(unsigned a, unsigned b, int c) {
#if __has_builtin(__builtin_amdgcn_sdot4)
    return __builtin_amdgcn_sdot4(a, b, c, false);
#else
    c += (int)(signed char)(a)        * (int)(signed char)(b);
    c += (int)(signed char)(a >> 8)   * (int)(signed char)(b >> 8);
    c += (int)(signed char)(a >> 16)  * (int)(signed char)(b >> 16);
    c += (int)(signed char)(a >> 24)  * (int)(signed char)(b >> 24);
    return c;
#endif
}

__device__ __forceinline__ int dot16(uv4 a, uv4 b) {
    int c = dot4(a.x, b.x, 0);
    c = dot4(a.y, b.y, c);
    c = dot4(a.z, b.z, c);
    return dot4(a.w, b.w, c);
}

// Kernel 1: per-node int8 quantization (q=rint(127 f/amax)) + invq=1/||q||.
__global__ void quantize_kernel(const float* __restrict__ feat,
                                unsigned short* __restrict__ tab16,
                                float* __restrict__ invq,
                                int num_nodes) {
    const int lane = threadIdx.x & 63;
    const int wpb = blockDim.x >> 6;
    int n = blockIdx.x * wpb + (threadIdx.x >> 6);
    const int stride = gridDim.x * wpb;
    for (; n < num_nodes; n += stride) {
        const float2 v = *reinterpret_cast<const float2*>(feat + (size_t)n * FEAT + lane * 2);
        float am = fmaxf(fabsf(v.x), fabsf(v.y));
        am = fmaxf(am, __shfl_xor(am, 32, 64));
        am = fmaxf(am, __shfl_xor(am, 16, 64));
        am = fmaxf(am, __shfl_xor(am, 8, 64));
        am = fmaxf(am, __shfl_xor(am, 4, 64));
        am = fmaxf(am, __shfl_xor(am, 2, 64));
        am = fmaxf(am, __shfl_xor(am, 1, 64));
        const float sc = (am > 0.0f) ? (127.0f / am) : 0.0f;
        const int qx = (int)rintf(v.x * sc);
        const int qy = (int)rintf(v.y * sc);
        int nq = qx * qx + qy * qy;
        nq += __shfl_xor(nq, 32, 64);
        nq += __shfl_xor(nq, 16, 64);
        nq += __shfl_xor(nq, 8, 64);
        nq += __shfl_xor(nq, 4, 64);
        nq += __shfl_xor(nq, 2, 64);
        nq += __shfl_xor(nq, 1, 64);
        tab16[(size_t)n * (FEAT / 2) + lane] =
            (unsigned short)((qx & 0xFF) | ((qy & 0xFF) << 8));
        if (lane == 0)
            invq[n] = (nq > 0) ? (1.0f / sqrtf((float)nq)) : 0.0f;
    }
}

// Kernel 2 (phase 1): per-edge cosine -> u16 fixed-point array. NO atomics.
// 8 lanes/edge-group, 4 consecutive edges/group; group leader stores ushort4.
__global__ void edge_i8_sim(const unsigned char* __restrict__ tab,
                            const int* __restrict__ ei,
                            const float* __restrict__ invq,
                            unsigned short* __restrict__ sim,
                            int num_edges, int aligned4) {
    const int sub = threadIdx.x & 7;
    const int gid = blockIdx.x * (blockDim.x >> 3) + (threadIdx.x >> 3);
    const int e0 = gid * EPG;
    if (e0 >= num_edges) return;

    int s[EPG], d[EPG];
    const bool fast = aligned4 && (e0 + EPG <= num_edges);
    if (fast) {
        const uv4 si = *(const uv4*)(ei + e0);
        const uv4 di = *(const uv4*)(ei + (size_t)num_edges + e0);
        s[0] = (int)si.x; s[1] = (int)si.y; s[2] = (int)si.z; s[3] = (int)si.w;
        d[0] = (int)di.x; d[1] = (int)di.y; d[2] = (int)di.z; d[3] = (int)di.w;
    } else {
#pragma unroll
        for (int k = 0; k < EPG; ++k) {
            const int e = min(e0 + k, num_edges - 1);
            s[k] = ei[e];
            d[k] = ei[(size_t)num_edges + e];
        }
    }

    uv4 a[EPG], b[EPG];
#pragma unroll
    for (int k = 0; k < EPG; ++k) {
        a[k] = *(const uv4*)(tab + (size_t)s[k] * FEAT + sub * 16);
        b[k] = *(const uv4*)(tab + (size_t)d[k] * FEAT + sub * 16);
    }

    int p[EPG];
#pragma unroll
    for (int k = 0; k < EPG; ++k) p[k] = dot16(a[k], b[k]);
#pragma unroll
    for (int k = 0; k < EPG; ++k) {
        p[k] += __shfl_xor(p[k], 1, 64);
        p[k] += __shfl_xor(p[k], 2, 64);
        p[k] += __shfl_xor(p[k], 4, 64);
    }

    // lanes 2k/2k+1 load the two endpoints' invq of edge k; pair-product
    int myidx = s[0];
    if (sub == 1) myidx = d[0];
    else if (sub == 2) myidx = s[1];
    else if (sub == 3) myidx = d[1];
    else if (sub == 4) myidx = s[2];
    else if (sub == 5) myidx = d[2];
    else if (sub == 6) myidx = s[3];
    else if (sub == 7) myidx = d[3];

    const float msc = invq[myidx];
    const float prod = msc * __shfl_xor(msc, 1, 64);   // invq_s * invq_d (lanes 2k,2k+1)

    const int gb = (threadIdx.x & 63) & ~7;            // group base within wave
    const float pr0 = __shfl(prod, gb + 0, 64);
    const float pr1 = __shfl(prod, gb + 2, 64);
    const float pr2 = __shfl(prod, gb + 4, 64);
    const float pr3 = __shfl(prod, gb + 6, 64);

    if (sub == 0) {
        // (sim+2)*2^14 = dot*prod*2^14 + 2^15; sim<=1 by Cauchy-Schwarz -> <=49152
        us4 o;
        o.x = (unsigned short)((float)p[0] * pr0 * SIM_SCALE + 32768.5f);
        o.y = (unsigned short)((float)p[1] * pr1 * SIM_SCALE + 32768.5f);
        o.z = (unsigned short)((float)p[2] * pr2 * SIM_SCALE + 32768.5f);
        o.w = (unsigned short)((float)p[3] * pr3 * SIM_SCALE + 32768.5f);
        *(us4*)(sim + e0) = o;     // e0 multiple of 4 -> 8B aligned; pad covers tail
    }
}

// Kernel 3 (phase 2): LDS aggregation sweep. Block = (chunk, slice).
// Sweeps its slice of the edge list; accumulates in-range endpoints into a
// 64KB LDS table via LDS atomics; flushes to its own slice plane (no global
// atomics anywhere).
__global__ __launch_bounds__(1024)
void agg_kernel(const int* __restrict__ ei,
                const unsigned short* __restrict__ sim,
                unsigned* __restrict__ acc,
                int num_edges, int num_nodes, int CH, int S, int aligned4) {
    __shared__ unsigned lds[CHN];
    const int slice = blockIdx.x / CH;
    const int chunk = blockIdx.x % CH;
    const int base = chunk * CHN;
    const int cn = min(CHN, num_nodes - base);

    for (int i = threadIdx.x; i < cn; i += blockDim.x) lds[i] = 0;
    __syncthreads();

    const int P = (num_edges + 3) >> 2;                 // 4-edge packets
    const int p0 = (int)((long long)P * slice / S);
    const int p1 = (int)((long long)P * (slice + 1) / S);

    for (int p = p0 + threadIdx.x; p < p1; p += blockDim.x) {
        const int e0 = p * 4;
        if (aligned4 && (e0 + 3 < num_edges)) {
            const uv4 su = *(const uv4*)(ei + e0);
            const uv4 du = *(const uv4*)(ei + (size_t)num_edges + e0);
            const us4 sm = *(const us4*)(sim + e0);
#pragma unroll
            for (int k = 0; k < 4; ++k) {
                const unsigned v = (1u << CNT_SHIFT) | (unsigned)sm[k];
                const unsigned cs = (unsigned)((int)su[k] - base);
                const unsigned cd = (unsigned)((int)du[k] - base);
                if (cs < (unsigned)cn) atomicAdd(&lds[cs], v);
                if (cd < (unsigned)cn) atomicAdd(&lds[cd], v);
            }
        } else {
#pragma unroll
            for (int k = 0; k < 4; ++k) {
                const int e = e0 + k;
                if (e < num_edges) {
                    const unsigned v = (1u << CNT_SHIFT) | (unsigned)sim[e];
                    const unsigned cs = (unsigned)(ei[e] - base);
                    const unsigned cd = (unsigned)(ei[(size_t)num_edges + e] - base);
                    if (cs < (unsigned)cn) atomicAdd(&lds[cs], v);
                    if (cd < (unsigned)cn) atomicAdd(&lds[cd], v);
                }
            }
        }
    }
    __syncthreads();
    for (int i = threadIdx.x; i < cn; i += blockDim.x)
        acc[(size_t)slice * num_nodes + base + i] = lds[i];
}

// Fallback phase-1+2 fused: global packed atomics (used only if ws too small).
__global__ void edge_i8_atomic(const unsigned char* __restrict__ tab,
                               const int* __restrict__ ei,
                               const float* __restrict__ invq,
                               unsigned* __restrict__ acc,
                               int num_edges, int aligned4) {
    const int sub = threadIdx.x & 7;
    const int gid = blockIdx.x * (blockDim.x >> 3) + (threadIdx.x >> 3);
    const int e0 = gid * EPG;
    if (e0 >= num_edges) return;
    int s[EPG], d[EPG];
    const bool fast = aligned4 && (e0 + EPG <= num_edges);
    if (fast) {
        const uv4 si = *(const uv4*)(ei + e0);
        const uv4 di = *(const uv4*)(ei + (size_t)num_edges + e0);
        s[0] = (int)si.x; s[1] = (int)si.y; s[2] = (int)si.z; s[3] = (int)si.w;
        d[0] = (int)di.x; d[1] = (int)di.y; d[2] = (int)di.z; d[3] = (int)di.w;
    } else {
#pragma unroll
        for (int k = 0; k < EPG; ++k) {
            const int e = min(e0 + k, num_edges - 1);
            s[k] = ei[e];
            d[k] = ei[(size_t)num_edges + e];
        }
    }
    uv4 a[EPG], b[EPG];
#pragma unroll
    for (int k = 0; k < EPG; ++k) {
        a[k] = *(const uv4*)(tab + (size_t)s[k] * FEAT + sub * 16);
        b[k] = *(const uv4*)(tab + (size_t)d[k] * FEAT + sub * 16);
    }
    int p[EPG];
#pragma unroll
    for (int k = 0; k < EPG; ++k) p[k] = dot16(a[k], b[k]);
#pragma unroll
    for (int k = 0; k < EPG; ++k) {
        p[k] += __shfl_xor(p[k], 1, 64);
        p[k] += __shfl_xor(p[k], 2, 64);
        p[k] += __shfl_xor(p[k], 4, 64);
    }
    int myidx = s[0];
    if (sub == 1) myidx = d[0];
    else if (sub == 2) myidx = s[1];
    else if (sub == 3) myidx = d[1];
    else if (sub == 4) myidx = s[2];
    else if (sub == 5) myidx = d[2];
    else if (sub == 6) myidx = s[3];
    else if (sub == 7) myidx = d[3];
    int mydot = p[0];
    if (sub >= 6) mydot = p[3];
    else if (sub >= 4) mydot = p[2];
    else if (sub >= 2) mydot = p[1];
    const float msc = invq[myidx];
    const float prod = msc * __shfl_xor(msc, 1, 64);
    if (fast || (e0 + (sub >> 1)) < num_edges) {
        const unsigned pk = (1u << CNT_SHIFT) |
            (unsigned)((float)mydot * prod * SIM_SCALE + 32768.5f);
        atomicAdd(&acc[myidx], pk);
    }
}

// Kernel 4: decode across S slice planes.
__global__ void final_kernel(const unsigned* __restrict__ acc,
                             float* __restrict__ out,
                             int num_nodes, int S) {
    const int i = blockIdx.x * blockDim.x + threadIdx.x;
    if (i < num_nodes) {
        unsigned cnt = 0, fx = 0;
        for (int c = 0; c < S; ++c) {
            const unsigned x = acc[(size_t)c * num_nodes + i];
            cnt += x >> CNT_SHIFT;
            fx += x & ((1u << CNT_SHIFT) - 1u);
        }
        out[i] = cnt ? ((float)fx * INV_SIM - 2.0f * (float)cnt) / (float)cnt : 1.0f;
    }
}

extern "C" void kernel_launch(void* const* d_in, const int* in_sizes, int n_in,
                              void* d_out, int out_size, void* d_ws, size_t ws_size,
                              hipStream_t stream) {
    const float* feat = (const float*)d_in[0];
    const int* ei = (const int*)d_in[1];
    const int num_nodes = in_sizes[0] / FEAT;     // 100000
    const int num_edges = in_sizes[1] / 2;        // 1600000
    float* out = (float*)d_out;
    const int aligned4 = ((num_edges & 3) == 0) ? 1 : 0;

    // ws layout: [sim u16 padE] [invq f32 N] [tab i8 N*128] [acc u32 S*N]
    const size_t padE = (size_t)((num_edges + 3) & ~3) + 4;
    const size_t off_invq = padE * sizeof(unsigned short);
    const size_t off_tab = off_invq + (size_t)num_nodes * sizeof(float);
    const size_t off_acc = off_tab + (size_t)num_nodes * FEAT;

    unsigned short* sim = (unsigned short*)d_ws;
    float* invq = (float*)((char*)d_ws + off_invq);
    unsigned short* tab16 = (unsigned short*)((char*)d_ws + off_tab);
    unsigned* acc = (unsigned*)((char*)d_ws + off_acc);

    int S = 0;
    if (ws_size > off_acc) {
        const size_t avail = ws_size - off_acc;
        size_t smax = avail / ((size_t)num_nodes * sizeof(unsigned));
        S = (int)((smax > 72) ? 72 : smax);
    }
    const int CH = (num_nodes + CHN - 1) / CHN;   // 7 chunks

    // quantize (always needed)
    {
        const int wpb = 4;
        int blocks = (num_nodes + wpb - 1) / wpb;
        if (blocks > 25000) blocks = 25000;
        quantize_kernel<<<blocks, 256, 0, stream>>>(feat, tab16, invq, num_nodes);
    }

    if (S >= 8 && aligned4) {
        // main: phase 1 (no atomics) + LDS aggregation sweep + decode
        {
            const int epb = (256 / 8) * EPG;                  // 128 edges/block
            const int blocks = (num_edges + epb - 1) / epb;
            edge_i8_sim<<<blocks, 256, 0, stream>>>(
                (const unsigned char*)tab16, ei, invq, sim, num_edges, aligned4);
        }
        agg_kernel<<<CH * S, 1024, 0, stream>>>(ei, sim, acc, num_edges,
                                                num_nodes, CH, S, aligned4);
        final_kernel<<<(num_nodes + 255) / 256, 256, 0, stream>>>(acc, out, num_nodes, S);
    } else {
        // fallback: fused atomic path (single acc plane)
        hipMemsetAsync(acc, 0, (size_t)num_nodes * sizeof(unsigned), stream);
        {
            const int epb = (256 / 8) * EPG;
            const int blocks = (num_edges + epb - 1) / epb;
            edge_i8_atomic<<<blocks, 256, 0, stream>>>(
                (const unsigned char*)tab16, ei, invq, acc, num_edges, aligned4);
        }
        final_kernel<<<(num_nodes + 255) / 256, 256, 0, stream>>>(acc, out, num_nodes, 1);
    }
}

// Round 9
// 134.973 us; speedup vs baseline: 1.2756x; 1.1240x over previous
//
#include <hip/hip_runtime.h>

#define FEAT 128              // elements per row (int8 row = 128 bytes)
#define EPG 4                 // edges per 8-lane group
#define CHN 25000             // nodes per LDS chunk (100000 B static LDS, CH=4)
#define CNT_SHIFT 24          // count in bits [24..31] of packed u32
#define SIM_SCALE 16384.0f    // 2^14 fixed point for (sim+2) in [0,3.0] -> <= 49152 (u16)
#define INV_SIM (1.0f/16384.0f)
#define EPS 1e-8f

typedef unsigned uv4 __attribute__((ext_vector_type(4)));
typedef unsigned short us4 __attribute__((ext_vector_type(4)));

__device__ __forceinline__ int dot4(unsigned a, unsigned b, int c) {
#if __has_builtin(__builtin_amdgcn_sdot4)
    return __builtin_amdgcn_sdot4(a, b, c, false);
#else
    c += (int)(signed char)(a)        * (int)(signed char)(b);
    c += (int)(signed char)(a >> 8)   * (int)(signed char)(b >> 8);
    c += (int)(signed char)(a >> 16)  * (int)(signed char)(b >> 16);
    c += (int)(signed char)(a >> 24)  * (int)(signed char)(b >> 24);
    return c;
#endif
}

__device__ __forceinline__ int dot16(uv4 a, uv4 b) {
    int c = dot4(a.x, b.x, 0);
    c = dot4(a.y, b.y, c);
    c = dot4(a.z, b.z, c);
    return dot4(a.w, b.w, c);
}

// Kernel 1: int8 quantization, 32 lanes per row. Lane j loads float4 (16B),
// packs its own 4 int8 -> one u32 store. amax/norm reduced over the 32-group.
__global__ void quantize_kernel(const float* __restrict__ feat,
                                unsigned* __restrict__ tab32,
                                float* __restrict__ invq,
                                int num_nodes) {
    const int sub = threadIdx.x & 31;
    const int hpb = blockDim.x >> 5;           // rows per block pass
    int n = blockIdx.x * hpb + (threadIdx.x >> 5);
    const int stride = gridDim.x * hpb;
    for (; n < num_nodes; n += stride) {
        const float4 v = *reinterpret_cast<const float4*>(feat + (size_t)n * FEAT + sub * 4);
        float am = fmaxf(fmaxf(fabsf(v.x), fabsf(v.y)), fmaxf(fabsf(v.z), fabsf(v.w)));
        am = fmaxf(am, __shfl_xor(am, 16, 64));
        am = fmaxf(am, __shfl_xor(am, 8, 64));
        am = fmaxf(am, __shfl_xor(am, 4, 64));
        am = fmaxf(am, __shfl_xor(am, 2, 64));
        am = fmaxf(am, __shfl_xor(am, 1, 64));
        const float sc = (am > 0.0f) ? (127.0f / am) : 0.0f;
        const int q0 = (int)rintf(v.x * sc);
        const int q1 = (int)rintf(v.y * sc);
        const int q2 = (int)rintf(v.z * sc);
        const int q3 = (int)rintf(v.w * sc);
        int nq = q0 * q0 + q1 * q1 + q2 * q2 + q3 * q3;
        nq += __shfl_xor(nq, 16, 64);
        nq += __shfl_xor(nq, 8, 64);
        nq += __shfl_xor(nq, 4, 64);
        nq += __shfl_xor(nq, 2, 64);
        nq += __shfl_xor(nq, 1, 64);
        tab32[(size_t)n * (FEAT / 4) + sub] =
            (unsigned)(q0 & 0xFF) | ((unsigned)(q1 & 0xFF) << 8) |
            ((unsigned)(q2 & 0xFF) << 16) | ((unsigned)(q3 & 0xFF) << 24);
        if (sub == 0)
            invq[n] = (nq > 0) ? (1.0f / sqrtf((float)nq)) : 0.0f;
    }
}

// Kernel 2 (phase 1): per-edge cosine -> u16 fixed-point array. NO atomics.
__global__ void edge_i8_sim(const unsigned char* __restrict__ tab,
                            const int* __restrict__ ei,
                            const float* __restrict__ invq,
                            unsigned short* __restrict__ sim,
                            int num_edges, int aligned4) {
    const int sub = threadIdx.x & 7;
    const int gid = blockIdx.x * (blockDim.x >> 3) + (threadIdx.x >> 3);
    const int e0 = gid * EPG;
    if (e0 >= num_edges) return;

    int s[EPG], d[EPG];
    const bool fast = aligned4 && (e0 + EPG <= num_edges);
    if (fast) {
        const uv4 si = *(const uv4*)(ei + e0);
        const uv4 di = *(const uv4*)(ei + (size_t)num_edges + e0);
        s[0] = (int)si.x; s[1] = (int)si.y; s[2] = (int)si.z; s[3] = (int)si.w;
        d[0] = (int)di.x; d[1] = (int)di.y; d[2] = (int)di.z; d[3] = (int)di.w;
    } else {
#pragma unroll
        for (int k = 0; k < EPG; ++k) {
            const int e = min(e0 + k, num_edges - 1);
            s[k] = ei[e];
            d[k] = ei[(size_t)num_edges + e];
        }
    }

    uv4 a[EPG], b[EPG];
#pragma unroll
    for (int k = 0; k < EPG; ++k) {
        a[k] = *(const uv4*)(tab + (size_t)s[k] * FEAT + sub * 16);
        b[k] = *(const uv4*)(tab + (size_t)d[k] * FEAT + sub * 16);
    }

    int p[EPG];
#pragma unroll
    for (int k = 0; k < EPG; ++k) p[k] = dot16(a[k], b[k]);
#pragma unroll
    for (int k = 0; k < EPG; ++k) {
        p[k] += __shfl_xor(p[k], 1, 64);
        p[k] += __shfl_xor(p[k], 2, 64);
        p[k] += __shfl_xor(p[k], 4, 64);
    }

    int myidx = s[0];
    if (sub == 1) myidx = d[0];
    else if (sub == 2) myidx = s[1];
    else if (sub == 3) myidx = d[1];
    else if (sub == 4) myidx = s[2];
    else if (sub == 5) myidx = d[2];
    else if (sub == 6) myidx = s[3];
    else if (sub == 7) myidx = d[3];

    const float msc = invq[myidx];
    const float prod = msc * __shfl_xor(msc, 1, 64);   // invq_s * invq_d on lanes 2k

    const int gb = (threadIdx.x & 63) & ~7;
    const float pr0 = __shfl(prod, gb + 0, 64);
    const float pr1 = __shfl(prod, gb + 2, 64);
    const float pr2 = __shfl(prod, gb + 4, 64);
    const float pr3 = __shfl(prod, gb + 6, 64);

    if (sub == 0) {
        us4 o;
        o.x = (unsigned short)((float)p[0] * pr0 * SIM_SCALE + 32768.5f);
        o.y = (unsigned short)((float)p[1] * pr1 * SIM_SCALE + 32768.5f);
        o.z = (unsigned short)((float)p[2] * pr2 * SIM_SCALE + 32768.5f);
        o.w = (unsigned short)((float)p[3] * pr3 * SIM_SCALE + 32768.5f);
        *(us4*)(sim + e0) = o;
    }
}

// Kernel 3 (phase 2): LDS aggregation sweep. Block = (chunk, slice).
// 100 KB LDS table per block (1 block/CU); CH=4 chunks -> sweep = 4x edge list.
__global__ __launch_bounds__(1024)
void agg_kernel(const int* __restrict__ ei,
                const unsigned short* __restrict__ sim,
                unsigned* __restrict__ acc,
                int num_edges, int num_nodes, int CH, int S, int aligned4) {
    __shared__ unsigned lds[CHN];
    const int slice = blockIdx.x / CH;
    const int chunk = blockIdx.x % CH;
    const int base = chunk * CHN;
    const int cn = min(CHN, num_nodes - base);

    for (int i = threadIdx.x; i < cn; i += blockDim.x) lds[i] = 0;
    __syncthreads();

    const int P = (num_edges + 3) >> 2;                 // 4-edge packets
    const int p0 = (int)((long long)P * slice / S);
    const int p1 = (int)((long long)P * (slice + 1) / S);

    for (int p = p0 + threadIdx.x; p < p1; p += blockDim.x) {
        const int e0 = p * 4;
        if (aligned4 && (e0 + 3 < num_edges)) {
            const uv4 su = *(const uv4*)(ei + e0);
            const uv4 du = *(const uv4*)(ei + (size_t)num_edges + e0);
            const us4 sm = *(const us4*)(sim + e0);
#pragma unroll
            for (int k = 0; k < 4; ++k) {
                const unsigned v = (1u << CNT_SHIFT) | (unsigned)sm[k];
                const unsigned cs = (unsigned)((int)su[k] - base);
                const unsigned cd = (unsigned)((int)du[k] - base);
                if (cs < (unsigned)cn) atomicAdd(&lds[cs], v);
                if (cd < (unsigned)cn) atomicAdd(&lds[cd], v);
            }
        } else {
#pragma unroll
            for (int k = 0; k < 4; ++k) {
                const int e = e0 + k;
                if (e < num_edges) {
                    const unsigned v = (1u << CNT_SHIFT) | (unsigned)sim[e];
                    const unsigned cs = (unsigned)(ei[e] - base);
                    const unsigned cd = (unsigned)(ei[(size_t)num_edges + e] - base);
                    if (cs < (unsigned)cn) atomicAdd(&lds[cs], v);
                    if (cd < (unsigned)cn) atomicAdd(&lds[cd], v);
                }
            }
        }
    }
    __syncthreads();
    for (int i = threadIdx.x; i < cn; i += blockDim.x)
        acc[(size_t)slice * num_nodes + base + i] = lds[i];
}

// Fallback fused path: global packed atomics (used only if ws too small).
__global__ void edge_i8_atomic(const unsigned char* __restrict__ tab,
                               const int* __restrict__ ei,
                               const float* __restrict__ invq,
                               unsigned* __restrict__ acc,
                               int num_edges, int aligned4) {
    const int sub = threadIdx.x & 7;
    const int gid = blockIdx.x * (blockDim.x >> 3) + (threadIdx.x >> 3);
    const int e0 = gid * EPG;
    if (e0 >= num_edges) return;
    int s[EPG], d[EPG];
    const bool fast = aligned4 && (e0 + EPG <= num_edges);
    if (fast) {
        const uv4 si = *(const uv4*)(ei + e0);
        const uv4 di = *(const uv4*)(ei + (size_t)num_edges + e0);
        s[0] = (int)si.x; s[1] = (int)si.y; s[2] = (int)si.z; s[3] = (int)si.w;
        d[0] = (int)di.x; d[1] = (int)di.y; d[2] = (int)di.z; d[3] = (int)di.w;
    } else {
#pragma unroll
        for (int k = 0; k < EPG; ++k) {
            const int e = min(e0 + k, num_edges - 1);
            s[k] = ei[e];
            d[k] = ei[(size_t)num_edges + e];
        }
    }
    uv4 a[EPG], b[EPG];
#pragma unroll
    for (int k = 0; k < EPG; ++k) {
        a[k] = *(const uv4*)(tab + (size_t)s[k] * FEAT + sub * 16);
        b[k] = *(const uv4*)(tab + (size_t)d[k] * FEAT + sub * 16);
    }
    int p[EPG];
#pragma unroll
    for (int k = 0; k < EPG; ++k) p[k] = dot16(a[k], b[k]);
#pragma unroll
    for (int k = 0; k < EPG; ++k) {
        p[k] += __shfl_xor(p[k], 1, 64);
        p[k] += __shfl_xor(p[k], 2, 64);
        p[k] += __shfl_xor(p[k], 4, 64);
    }
    int myidx = s[0];
    if (sub == 1) myidx = d[0];
    else if (sub == 2) myidx = s[1];
    else if (sub == 3) myidx = d[1];
    else if (sub == 4) myidx = s[2];
    else if (sub == 5) myidx = d[2];
    else if (sub == 6) myidx = s[3];
    else if (sub == 7) myidx = d[3];
    int mydot = p[0];
    if (sub >= 6) mydot = p[3];
    else if (sub >= 4) mydot = p[2];
    else if (sub >= 2) mydot = p[1];
    const float msc = invq[myidx];
    const float prod = msc * __shfl_xor(msc, 1, 64);
    if (fast || (e0 + (sub >> 1)) < num_edges) {
        const unsigned pk = (1u << CNT_SHIFT) |
            (unsigned)((float)mydot * prod * SIM_SCALE + 32768.5f);
        atomicAdd(&acc[myidx], pk);
    }
}

// Kernel 4: decode across S slice planes.
__global__ void final_kernel(const unsigned* __restrict__ acc,
                             float* __restrict__ out,
                             int num_nodes, int S) {
    const int i = blockIdx.x * blockDim.x + threadIdx.x;
    if (i < num_nodes) {
        unsigned cnt = 0, fx = 0;
        for (int c = 0; c < S; ++c) {
            const unsigned x = acc[(size_t)c * num_nodes + i];
            cnt += x >> CNT_SHIFT;
            fx += x & ((1u << CNT_SHIFT) - 1u);
        }
        out[i] = cnt ? ((float)fx * INV_SIM - 2.0f * (float)cnt) / (float)cnt : 1.0f;
    }
}

extern "C" void kernel_launch(void* const* d_in, const int* in_sizes, int n_in,
                              void* d_out, int out_size, void* d_ws, size_t ws_size,
                              hipStream_t stream) {
    const float* feat = (const float*)d_in[0];
    const int* ei = (const int*)d_in[1];
    const int num_nodes = in_sizes[0] / FEAT;     // 100000
    const int num_edges = in_sizes[1] / 2;        // 1600000
    float* out = (float*)d_out;
    const int aligned4 = ((num_edges & 3) == 0) ? 1 : 0;

    // ws layout: [sim u16 padE] [invq f32 N] [tab i8 N*128] [acc u32 S*N]
    const size_t padE = (size_t)((num_edges + 3) & ~3) + 4;
    const size_t off_invq = padE * sizeof(unsigned short);
    const size_t off_tab = off_invq + (size_t)num_nodes * sizeof(float);
    const size_t off_acc = off_tab + (size_t)num_nodes * FEAT;

    unsigned short* sim = (unsigned short*)d_ws;
    float* invq = (float*)((char*)d_ws + off_invq);
    unsigned* tab32 = (unsigned*)((char*)d_ws + off_tab);
    unsigned* acc = (unsigned*)((char*)d_ws + off_acc);

    int S = 0;
    if (ws_size > off_acc) {
        const size_t avail = ws_size - off_acc;
        size_t smax = avail / ((size_t)num_nodes * sizeof(unsigned));
        S = (int)((smax > 64) ? 64 : smax);
    }
    const int CH = (num_nodes + CHN - 1) / CHN;   // 4 chunks at N=100000

    // quantize (always needed): 32 lanes/row, 8 rows per 256-thread block
    {
        const int hpb = 8;
        int blocks = (num_nodes + hpb - 1) / hpb;
        quantize_kernel<<<blocks, 256, 0, stream>>>(feat, tab32, invq, num_nodes);
    }

    if (S >= 8 && aligned4) {
        {
            const int epb = (256 / 8) * EPG;                  // 128 edges/block
            const int blocks = (num_edges + epb - 1) / epb;
            edge_i8_sim<<<blocks, 256, 0, stream>>>(
                (const unsigned char*)tab32, ei, invq, sim, num_edges, aligned4);
        }
        agg_kernel<<<CH * S, 1024, 0, stream>>>(ei, sim, acc, num_edges,
                                                num_nodes, CH, S, aligned4);
        final_kernel<<<(num_nodes + 255) / 256, 256, 0, stream>>>(acc, out, num_nodes, S);
    } else {
        hipMemsetAsync(acc, 0, (size_t)num_nodes * sizeof(unsigned), stream);
        {
            const int epb = (256 / 8) * EPG;
            const int blocks = (num_edges + epb - 1) / epb;
            edge_i8_atomic<<<blocks, 256, 0, stream>>>(
                (const unsigned char*)tab32, ei, invq, acc, num_edges, aligned4);
        }
        final_kernel<<<(num_nodes + 255) / 256, 256, 0, stream>>>(acc, out, num_nodes, 1);
    }
}